// Round 4
// baseline (93.727 us; speedup 1.0000x reference)
//
#include <hip/hip_runtime.h>

#define FXc 160.0f
#define FYc 160.0f
#define THRESHc 0.001f
#define EPSc 1e-6f
#define NSEG 16
#define TILE 16
#define CH 128
#define SORT_CAP 2048
#define PTH 128

// ---- fused preprocess + O(N^2) rank (stable) + scatter ----------------------
// Each block stages ALL n depths into LDS (recomputed identically per block),
// each thread ranks its own gaussian against all n, then computes full 2D
// params and scatters straight to the depth-sorted slot.
__global__ __launch_bounds__(PTH) void prep_rank_kernel(
    const float* __restrict__ mean, const float* __restrict__ qvec,
    const float* __restrict__ svec, const float* __restrict__ color,
    const float* __restrict__ alpha, const float* __restrict__ c2w,
    float4* __restrict__ s0, float4* __restrict__ s1,
    float4* __restrict__ sbb, float* __restrict__ sa, int n) {
    __shared__ float dep[SORT_CAP];
    int tid = threadIdx.x;
    int gid = blockIdx.x * PTH + tid;

    float tx = c2w[3], ty = c2w[7], tz = c2w[11];
    float W00 = c2w[0], W01 = c2w[4], W02 = c2w[8];
    float W10 = c2w[1], W11 = c2w[5], W12 = c2w[9];
    float W20 = c2w[2], W21 = c2w[6], W22 = c2w[10];

    // all depths (identical arithmetic in every block -> consistent ranks)
    int ncap = (n + 3) & ~3;
    for (int i = tid; i < ncap; i += PTH) {
        float d = 3.0e38f;
        if (i < n) {
            float mx = mean[3*i+0] - tx, my = mean[3*i+1] - ty, mz = mean[3*i+2] - tz;
            d = W20*mx + W21*my + W22*mz;
        }
        dep[i] = d;
    }
    __syncthreads();

    if (gid >= n) return;

    float di = dep[gid];
    int rank = 0;
    const float4* dv = (const float4*)dep;
    int nj4 = ncap >> 2;
#pragma unroll 8
    for (int j4 = 0; j4 < nj4; ++j4) {
        float4 d = dv[j4];
        int j = j4 << 2;
        rank += (d.x < di || (d.x == di && (j + 0) < gid));
        rank += (d.y < di || (d.y == di && (j + 1) < gid));
        rank += (d.z < di || (d.z == di && (j + 2) < gid));
        rank += (d.w < di || (d.w == di && (j + 3) < gid));
    }

    // full params for own gaussian
    int i = gid;
    float mx = mean[3*i+0] - tx, my = mean[3*i+1] - ty, mz = mean[3*i+2] - tz;
    float pmx = W00*mx + W01*my + W02*mz;
    float pmy = W10*mx + W11*my + W12*mz;
    float pmz = W20*mx + W21*my + W22*mz;

    float qw = qvec[4*i+0], qx = qvec[4*i+1], qy = qvec[4*i+2], qz = qvec[4*i+3];
    float qinv = rsqrtf(qw*qw + qx*qx + qy*qy + qz*qz);
    qw *= qinv; qx *= qinv; qy *= qinv; qz *= qinv;
    float R00 = 1.0f - 2.0f*(qy*qy + qz*qz), R01 = 2.0f*(qx*qy - qw*qz), R02 = 2.0f*(qx*qz + qw*qy);
    float R10 = 2.0f*(qx*qy + qw*qz), R11 = 1.0f - 2.0f*(qx*qx + qz*qz), R12 = 2.0f*(qy*qz - qw*qx);
    float R20 = 2.0f*(qx*qz - qw*qy), R21 = 2.0f*(qy*qz + qw*qx), R22 = 1.0f - 2.0f*(qx*qx + qy*qy);
    float sx = svec[3*i+0], sy = svec[3*i+1], sz = svec[3*i+2];
    float M00 = R00*sx, M01 = R01*sy, M02 = R02*sz;
    float M10 = R10*sx, M11 = R11*sy, M12 = R12*sz;
    float M20 = R20*sx, M21 = R21*sy, M22 = R22*sz;

    float iz = 1.0f / pmz, iz2 = iz*iz;
    float axx = pmx*iz2, ayy = pmy*iz2;
    float A0 = iz*W00 - axx*W20, A1 = iz*W01 - axx*W21, A2 = iz*W02 - axx*W22;
    float B0 = iz*W10 - ayy*W20, B1 = iz*W11 - ayy*W21, B2 = iz*W12 - ayy*W22;
    float V00 = A0*M00 + A1*M10 + A2*M20;
    float V01 = A0*M01 + A1*M11 + A2*M21;
    float V02 = A0*M02 + A1*M12 + A2*M22;
    float V10 = B0*M00 + B1*M10 + B2*M20;
    float V11 = B0*M01 + B1*M11 + B2*M21;
    float V12 = B0*M02 + B1*M12 + B2*M22;
    float a  = V00*V00 + V01*V01 + V02*V02 + EPSc;
    float bb = V00*V10 + V01*V11 + V02*V12;
    float dd = V10*V10 + V11*V11 + V12*V12 + EPSc;
    float det  = a*dd - bb*bb;
    float idet = 1.0f / det;
    float h00 = -0.5f * dd * idet;
    float h01 =  bb * idet;
    float h11 = -0.5f * a  * idet;

    float al = alpha[i];
    float m2x = pmx*iz, m2y = pmy*iz;
    float x0, x1, y0, y1;
    if (al > THRESHc) {
        float c = logf(al / THRESHc);
        float ex = sqrtf(2.0f*c*a)  * 1.0009f + 1e-6f;
        float ey = sqrtf(2.0f*c*dd) * 1.0009f + 1e-6f;
        x0 = m2x - ex; x1 = m2x + ex;
        y0 = m2y - ey; y1 = m2y + ey;
    } else {
        x0 = 3.0e38f; x1 = -3.0e38f; y0 = 3.0e38f; y1 = -3.0e38f;
    }

    s0[rank]  = make_float4(m2x, m2y, h00, h01);
    s1[rank]  = make_float4(h11, color[3*i+0], color[3*i+1], color[3*i+2]);
    sbb[rank] = make_float4(x0, x1, y0, y1);
    sa[rank]  = al;
}

// ---- composite: one block = 16x16 tile x 1 depth segment -------------------
__global__ __launch_bounds__(256) void composite_kernel(
    const float4* __restrict__ s0, const float4* __restrict__ s1,
    const float4* __restrict__ sbb, const float* __restrict__ sa,
    const int* __restrict__ Wp, const int* __restrict__ Hp,
    float4* __restrict__ part, int n, int npix) {
    __shared__ float4 l0[CH], l1[CH], lb[CH];
    __shared__ float  la[CH];
    int W = *Wp, H = *Hp;
    int tilesX = (W + TILE - 1) / TILE;
    int tilesY = (H + TILE - 1) / TILE;
    int tile = blockIdx.x;
    if (tile >= tilesX * tilesY) return;   // uniform over block
    int seg = blockIdx.y;
    int seglen = (n + NSEG - 1) / NSEG;
    int gbeg = seg * seglen;
    int gend = min(n, gbeg + seglen);

    int tx = tile % tilesX, ty = tile / tilesX;
    int tid = threadIdx.x, wave = tid >> 6, lane = tid & 63;
    int qx = (wave & 1) * 8, qy = (wave >> 1) * 8;
    int lx = lane & 7, ly = lane >> 3;
    int col = tx * TILE + qx + lx;
    int row = ty * TILE + qy + ly;
    float cxofx = (W * 0.5f) / FXc, cyofy = (H * 0.5f) / FYc;
    float px = ((float)col + 0.5f) / FXc - cxofx;
    float py = ((float)row + 0.5f) / FYc - cyofy;
    float wx0 = ((float)(tx*TILE + qx) + 0.5f) / FXc - cxofx;
    float wx1 = ((float)(tx*TILE + qx + 7) + 0.5f) / FXc - cxofx;
    float wy0 = ((float)(ty*TILE + qy) + 0.5f) / FYc - cyofy;
    float wy1 = ((float)(ty*TILE + qy + 7) + 0.5f) / FYc - cyofy;

    float T = 1.0f, r = 0.0f, g = 0.0f, b = 0.0f;
    for (int base = gbeg; base < gend; base += CH) {
        int m = min(CH, gend - base);
        __syncthreads();
        for (int t = tid; t < m; t += 256) {
            l0[t] = s0[base + t];
            l1[t] = s1[base + t];
            lb[t] = sbb[base + t];
            la[t] = sa[base + t];
        }
        __syncthreads();
        for (int j = 0; j < m; ++j) {
            float4 bb = lb[j];
            // wave-uniform skip: bbox misses this wave's 8x8 quadrant entirely
            if (bb.y < wx0 || bb.x > wx1 || bb.w < wy0 || bb.z > wy1) continue;
            float4 a0 = l0[j];
            float4 a1 = l1[j];
            float  al = la[j];
            float dx = px - a0.x;
            float dy = py - a0.y;
            float pw = dx * (a0.z * dx + a0.w * dy) + a1.x * dy * dy;
            float w  = al * __expf(pw);
            w = fminf(w, 0.999f);
            w = (w > THRESHc) ? w : 0.0f;
            float wT = w * T;
            r = fmaf(wT, a1.y, r);
            g = fmaf(wT, a1.z, g);
            b = fmaf(wT, a1.w, b);
            T = T - wT;
        }
    }
    if (col < W && row < H) {
        int p = row * W + col;
        part[(size_t)seg * npix + p] = make_float4(r, g, b, T);
    }
}

// ---- combine segment partials front-to-back --------------------------------
__global__ __launch_bounds__(256) void combine_kernel(
    const float4* __restrict__ part, float* __restrict__ out, int npix) {
    int p = blockIdx.x * 256 + threadIdx.x;
    if (p >= npix) return;
    float T = 1.0f, r = 0.0f, g = 0.0f, b = 0.0f;
#pragma unroll
    for (int s = 0; s < NSEG; ++s) {
        float4 v = part[(size_t)s * npix + p];
        r = fmaf(T, v.x, r);
        g = fmaf(T, v.y, g);
        b = fmaf(T, v.z, b);
        T *= v.w;
    }
    out[3*p+0] = r;
    out[3*p+1] = g;
    out[3*p+2] = b;
}

extern "C" void kernel_launch(void* const* d_in, const int* in_sizes, int n_in,
                              void* d_out, int out_size, void* d_ws, size_t ws_size,
                              hipStream_t stream) {
    const float* mean  = (const float*)d_in[0];
    const float* qvec  = (const float*)d_in[1];
    const float* svec  = (const float*)d_in[2];
    const float* color = (const float*)d_in[3];
    const float* alpha = (const float*)d_in[4];
    const float* c2w   = (const float*)d_in[5];
    const int*   Hp    = (const int*)d_in[6];
    const int*   Wp    = (const int*)d_in[7];
    float* out = (float*)d_out;

    int n = in_sizes[0] / 3;
    int npix = out_size / 3;

    char* ws = (char*)d_ws;
    float4* s0  = (float4*)ws; ws += (size_t)n * sizeof(float4);
    float4* s1  = (float4*)ws; ws += (size_t)n * sizeof(float4);
    float4* sbb = (float4*)ws; ws += (size_t)n * sizeof(float4);
    float4* part = (float4*)ws; ws += (size_t)npix * NSEG * sizeof(float4);
    float* sa = (float*)ws; ws += (size_t)n * sizeof(float);

    prep_rank_kernel<<<(n + PTH - 1) / PTH, PTH, 0, stream>>>(
        mean, qvec, svec, color, alpha, c2w, s0, s1, sbb, sa, n);

    int Wh = 128;                       // problem constant; pixel coords still read W,H on-device
    int Hh = npix / Wh;
    int tiles = ((Wh + TILE - 1) / TILE) * ((Hh + TILE - 1) / TILE);
    dim3 grid(tiles, NSEG);
    composite_kernel<<<grid, 256, 0, stream>>>(s0, s1, sbb, sa, Wp, Hp, part, n, npix);

    combine_kernel<<<(npix + 255) / 256, 256, 0, stream>>>(part, out, npix);
}

// Round 5
// 46.129 us; speedup vs baseline: 2.0319x; 2.0319x over previous
//
#include <hip/hip_runtime.h>

#define FXc 160.0f
#define FYc 160.0f
#define THRESHc 0.001f
#define EPSc 1e-6f
#define SORT_CAP 2048

// ---- fused preprocess + wave-parallel O(N^2/64) rank + scatter --------------
// Block stages all n depths in LDS (one compute site -> bit-consistent ranks).
// One WAVE per gaussian: 64 lanes scan depths in parallel, rank via ballot
// popcount. Then all lanes redundantly compute params; lane 0 scatters to the
// depth-sorted slot.
__global__ __launch_bounds__(256) void prep_kernel(
    const float* __restrict__ mean, const float* __restrict__ qvec,
    const float* __restrict__ svec, const float* __restrict__ color,
    const float* __restrict__ alpha, const float* __restrict__ c2w,
    float4* __restrict__ s0, float4* __restrict__ s1,
    float4* __restrict__ sbb, float* __restrict__ sa, int n) {
    __shared__ float dep[SORT_CAP];
    int tid = threadIdx.x;
    int lane = tid & 63;
    int wv = tid >> 6;
    int i = blockIdx.x * 4 + wv;            // this wave's gaussian

    float tx = c2w[3], ty = c2w[7], tz = c2w[11];
    float W00 = c2w[0], W01 = c2w[4], W02 = c2w[8];
    float W10 = c2w[1], W11 = c2w[5], W12 = c2w[9];
    float W20 = c2w[2], W21 = c2w[6], W22 = c2w[10];

    int ncap = (n + 63) & ~63;
    for (int k = tid; k < ncap; k += 256) {
        float d = 3.0e38f;
        if (k < n) {
            float mx = mean[3*k+0] - tx, my = mean[3*k+1] - ty, mz = mean[3*k+2] - tz;
            d = W20*mx + W21*my + W22*mz;
        }
        dep[k] = d;
    }
    __syncthreads();
    if (i >= n) return;                     // wave-uniform

    float di = dep[i];                      // same stored bits everyone compares
    int nit = ncap >> 6;
    int rank = 0;
    for (int it = 0; it < nit; ++it) {
        int j = (it << 6) + lane;
        float dj = dep[j];
        bool c = (dj < di) || (dj == di && j < i);
        rank += (int)__popcll(__ballot(c));
    }

    // params for gaussian i (redundant across lanes; loads are broadcast)
    float mx = mean[3*i+0] - tx, my = mean[3*i+1] - ty, mz = mean[3*i+2] - tz;
    float pmx = W00*mx + W01*my + W02*mz;
    float pmy = W10*mx + W11*my + W12*mz;
    float pmz = W20*mx + W21*my + W22*mz;

    float qw = qvec[4*i+0], qx = qvec[4*i+1], qy = qvec[4*i+2], qz = qvec[4*i+3];
    float qinv = rsqrtf(qw*qw + qx*qx + qy*qy + qz*qz);
    qw *= qinv; qx *= qinv; qy *= qinv; qz *= qinv;
    float R00 = 1.0f - 2.0f*(qy*qy + qz*qz), R01 = 2.0f*(qx*qy - qw*qz), R02 = 2.0f*(qx*qz + qw*qy);
    float R10 = 2.0f*(qx*qy + qw*qz), R11 = 1.0f - 2.0f*(qx*qx + qz*qz), R12 = 2.0f*(qy*qz - qw*qx);
    float R20 = 2.0f*(qx*qz - qw*qy), R21 = 2.0f*(qy*qz + qw*qx), R22 = 1.0f - 2.0f*(qx*qx + qy*qy);
    float sx = svec[3*i+0], sy = svec[3*i+1], sz = svec[3*i+2];
    float M00 = R00*sx, M01 = R01*sy, M02 = R02*sz;
    float M10 = R10*sx, M11 = R11*sy, M12 = R12*sz;
    float M20 = R20*sx, M21 = R21*sy, M22 = R22*sz;

    float iz = 1.0f / pmz, iz2 = iz*iz;
    float axx = pmx*iz2, ayy = pmy*iz2;
    float A0 = iz*W00 - axx*W20, A1 = iz*W01 - axx*W21, A2 = iz*W02 - axx*W22;
    float B0 = iz*W10 - ayy*W20, B1 = iz*W11 - ayy*W21, B2 = iz*W12 - ayy*W22;
    float V00 = A0*M00 + A1*M10 + A2*M20;
    float V01 = A0*M01 + A1*M11 + A2*M21;
    float V02 = A0*M02 + A1*M12 + A2*M22;
    float V10 = B0*M00 + B1*M10 + B2*M20;
    float V11 = B0*M01 + B1*M11 + B2*M21;
    float V12 = B0*M02 + B1*M12 + B2*M22;
    float a  = V00*V00 + V01*V01 + V02*V02 + EPSc;
    float bb = V00*V10 + V01*V11 + V02*V12;
    float dd = V10*V10 + V11*V11 + V12*V12 + EPSc;
    float det  = a*dd - bb*bb;
    float idet = 1.0f / det;
    float h00 = -0.5f * dd * idet;
    float h01 =  bb * idet;
    float h11 = -0.5f * a  * idet;

    float al = alpha[i];
    float m2x = pmx*iz, m2y = pmy*iz;
    float x0, x1, y0, y1;
    if (al > THRESHc) {
        float c = logf(al / THRESHc);
        float ex = sqrtf(2.0f*c*a)  * 1.0009f + 1e-6f;
        float ey = sqrtf(2.0f*c*dd) * 1.0009f + 1e-6f;
        x0 = m2x - ex; x1 = m2x + ex;
        y0 = m2y - ey; y1 = m2y + ey;
    } else {
        x0 = 3.0e38f; x1 = -3.0e38f; y0 = 3.0e38f; y1 = -3.0e38f;
    }

    if (lane == 0) {
        s0[rank]  = make_float4(m2x, m2y, h00, h01);
        s1[rank]  = make_float4(h11, color[3*i+0], color[3*i+1], color[3*i+2]);
        sbb[rank] = make_float4(x0, x1, y0, y1);
        sa[rank]  = al;
    }
}

// ---- render: one wave per 8x8 pixel quadrant, ballot-compacted hit list -----
__global__ __launch_bounds__(64) void render_kernel(
    const float4* __restrict__ s0, const float4* __restrict__ s1,
    const float4* __restrict__ sbb, const float* __restrict__ sa,
    const int* __restrict__ Wp, const int* __restrict__ Hp,
    float* __restrict__ out, int n) {
    int lane = threadIdx.x;
    int W = *Wp, H = *Hp;
    int qpx = (W + 7) >> 3;
    int q = blockIdx.x;
    int qx = q % qpx, qy = q / qpx;
    int col = qx * 8 + (lane & 7);
    int row = qy * 8 + (lane >> 3);
    float cxofx = (W * 0.5f) / FXc, cyofy = (H * 0.5f) / FYc;
    float px = ((float)col + 0.5f) / FXc - cxofx;
    float py = ((float)row + 0.5f) / FYc - cyofy;
    // wave-uniform quadrant pixel-center bounds
    float wx0 = ((float)(qx*8)   + 0.5f) / FXc - cxofx;
    float wx1 = ((float)(qx*8+7) + 0.5f) / FXc - cxofx;
    float wy0 = ((float)(qy*8)   + 0.5f) / FYc - cyofy;
    float wy1 = ((float)(qy*8+7) + 0.5f) / FYc - cyofy;

    float T = 1.0f, r = 0.0f, g = 0.0f, b = 0.0f;
    int nit = (n + 63) >> 6;
    for (int it = 0; it < nit; ++it) {
        int j = (it << 6) + lane;
        bool hit = false;
        if (j < n) {
            float4 bbx = sbb[j];                       // coalesced float4
            hit = !(bbx.y < wx0 || bbx.x > wx1 || bbx.w < wy0 || bbx.z > wy1);
        }
        unsigned long long msk = __ballot(hit);
        int base = it << 6;
        while (msk) {                                  // ascending j = depth order
            int t = __builtin_ctzll(msk);
            msk &= msk - 1;
            int jj = base + t;
            float4 a0 = s0[jj];                        // uniform-address broadcast
            float4 a1 = s1[jj];
            float  al = sa[jj];
            float dx = px - a0.x;
            float dy = py - a0.y;
            float pw = dx * (a0.z * dx + a0.w * dy) + a1.x * dy * dy;
            float w  = al * __expf(pw);
            w = fminf(w, 0.999f);
            w = (w > THRESHc) ? w : 0.0f;
            float wT = w * T;
            r = fmaf(wT, a1.y, r);
            g = fmaf(wT, a1.z, g);
            b = fmaf(wT, a1.w, b);
            T = T - wT;
        }
        if (__all(T < 1e-5f)) break;                   // error <= 1e-5 << tol
    }
    if (col < W && row < H) {
        int p = row * W + col;
        out[3*p+0] = r;
        out[3*p+1] = g;
        out[3*p+2] = b;
    }
}

extern "C" void kernel_launch(void* const* d_in, const int* in_sizes, int n_in,
                              void* d_out, int out_size, void* d_ws, size_t ws_size,
                              hipStream_t stream) {
    const float* mean  = (const float*)d_in[0];
    const float* qvec  = (const float*)d_in[1];
    const float* svec  = (const float*)d_in[2];
    const float* color = (const float*)d_in[3];
    const float* alpha = (const float*)d_in[4];
    const float* c2w   = (const float*)d_in[5];
    const int*   Hp    = (const int*)d_in[6];
    const int*   Wp    = (const int*)d_in[7];
    float* out = (float*)d_out;

    int n = in_sizes[0] / 3;
    int npix = out_size / 3;

    char* ws = (char*)d_ws;
    float4* s0  = (float4*)ws; ws += (size_t)n * sizeof(float4);
    float4* s1  = (float4*)ws; ws += (size_t)n * sizeof(float4);
    float4* sbb = (float4*)ws; ws += (size_t)n * sizeof(float4);
    float*  sa  = (float*)ws;  ws += (size_t)n * sizeof(float);

    int nblocks = (n + 3) / 4;              // one wave (of 4/block) per gaussian
    prep_kernel<<<nblocks, 256, 0, stream>>>(mean, qvec, svec, color, alpha, c2w,
                                             s0, s1, sbb, sa, n);

    int Wh = 128;                           // problem constant; device code reads W,H
    int Hh = npix / Wh;
    int quads = ((Wh + 7) / 8) * ((Hh + 7) / 8);
    render_kernel<<<quads, 64, 0, stream>>>(s0, s1, sbb, sa, Wp, Hp, out, n);
}

// Round 6
// 19.124 us; speedup vs baseline: 4.9010x; 2.4121x over previous
//
#include <hip/hip_runtime.h>

#define FXc 160.0f
#define FYc 160.0f
#define THRESHc 0.001f
#define EPSc 1e-6f
#define SORT_CAP 2048
#define NSEG 16
#define CH 128            // max gaussians per segment staged in LDS

// ---- fused preprocess + wave-parallel rank + scatter (unchanged from R5) ----
__global__ __launch_bounds__(256) void prep_kernel(
    const float* __restrict__ mean, const float* __restrict__ qvec,
    const float* __restrict__ svec, const float* __restrict__ color,
    const float* __restrict__ alpha, const float* __restrict__ c2w,
    float4* __restrict__ s0, float4* __restrict__ s1,
    float4* __restrict__ sbb, float* __restrict__ sa, int n) {
    __shared__ float dep[SORT_CAP];
    int tid = threadIdx.x;
    int lane = tid & 63;
    int wv = tid >> 6;
    int i = blockIdx.x * 4 + wv;

    float tx = c2w[3], ty = c2w[7], tz = c2w[11];
    float W00 = c2w[0], W01 = c2w[4], W02 = c2w[8];
    float W10 = c2w[1], W11 = c2w[5], W12 = c2w[9];
    float W20 = c2w[2], W21 = c2w[6], W22 = c2w[10];

    int ncap = (n + 63) & ~63;
    for (int k = tid; k < ncap; k += 256) {
        float d = 3.0e38f;
        if (k < n) {
            float mx = mean[3*k+0] - tx, my = mean[3*k+1] - ty, mz = mean[3*k+2] - tz;
            d = W20*mx + W21*my + W22*mz;
        }
        dep[k] = d;
    }
    __syncthreads();
    if (i >= n) return;

    float di = dep[i];
    int nit = ncap >> 6;
    int rank = 0;
    for (int it = 0; it < nit; ++it) {
        int j = (it << 6) + lane;
        float dj = dep[j];
        bool c = (dj < di) || (dj == di && j < i);
        rank += (int)__popcll(__ballot(c));
    }

    float mx = mean[3*i+0] - tx, my = mean[3*i+1] - ty, mz = mean[3*i+2] - tz;
    float pmx = W00*mx + W01*my + W02*mz;
    float pmy = W10*mx + W11*my + W12*mz;
    float pmz = W20*mx + W21*my + W22*mz;

    float qw = qvec[4*i+0], qx = qvec[4*i+1], qy = qvec[4*i+2], qz = qvec[4*i+3];
    float qinv = rsqrtf(qw*qw + qx*qx + qy*qy + qz*qz);
    qw *= qinv; qx *= qinv; qy *= qinv; qz *= qinv;
    float R00 = 1.0f - 2.0f*(qy*qy + qz*qz), R01 = 2.0f*(qx*qy - qw*qz), R02 = 2.0f*(qx*qz + qw*qy);
    float R10 = 2.0f*(qx*qy + qw*qz), R11 = 1.0f - 2.0f*(qx*qx + qz*qz), R12 = 2.0f*(qy*qz - qw*qx);
    float R20 = 2.0f*(qx*qz - qw*qy), R21 = 2.0f*(qy*qz + qw*qx), R22 = 1.0f - 2.0f*(qx*qx + qy*qy);
    float sx = svec[3*i+0], sy = svec[3*i+1], sz = svec[3*i+2];
    float M00 = R00*sx, M01 = R01*sy, M02 = R02*sz;
    float M10 = R10*sx, M11 = R11*sy, M12 = R12*sz;
    float M20 = R20*sx, M21 = R21*sy, M22 = R22*sz;

    float iz = 1.0f / pmz, iz2 = iz*iz;
    float axx = pmx*iz2, ayy = pmy*iz2;
    float A0 = iz*W00 - axx*W20, A1 = iz*W01 - axx*W21, A2 = iz*W02 - axx*W22;
    float B0 = iz*W10 - ayy*W20, B1 = iz*W11 - ayy*W21, B2 = iz*W12 - ayy*W22;
    float V00 = A0*M00 + A1*M10 + A2*M20;
    float V01 = A0*M01 + A1*M11 + A2*M21;
    float V02 = A0*M02 + A1*M12 + A2*M22;
    float V10 = B0*M00 + B1*M10 + B2*M20;
    float V11 = B0*M01 + B1*M11 + B2*M21;
    float V12 = B0*M02 + B1*M12 + B2*M22;
    float a  = V00*V00 + V01*V01 + V02*V02 + EPSc;
    float bb = V00*V10 + V01*V11 + V02*V12;
    float dd = V10*V10 + V11*V11 + V12*V12 + EPSc;
    float det  = a*dd - bb*bb;
    float idet = 1.0f / det;
    float h00 = -0.5f * dd * idet;
    float h01 =  bb * idet;
    float h11 = -0.5f * a  * idet;

    float al = alpha[i];
    float m2x = pmx*iz, m2y = pmy*iz;
    float x0, x1, y0, y1;
    if (al > THRESHc) {
        float c = logf(al / THRESHc);
        float ex = sqrtf(2.0f*c*a)  * 1.0009f + 1e-6f;
        float ey = sqrtf(2.0f*c*dd) * 1.0009f + 1e-6f;
        x0 = m2x - ex; x1 = m2x + ex;
        y0 = m2y - ey; y1 = m2y + ey;
    } else {
        x0 = 3.0e38f; x1 = -3.0e38f; y0 = 3.0e38f; y1 = -3.0e38f;
    }

    if (lane == 0) {
        s0[rank]  = make_float4(m2x, m2y, h00, h01);
        s1[rank]  = make_float4(h11, color[3*i+0], color[3*i+1], color[3*i+2]);
        sbb[rank] = make_float4(x0, x1, y0, y1);
        sa[rank]  = al;
    }
}

// ---- composite: block = 4 quadrants x 1 segment; LDS-staged SoA ------------
__global__ __launch_bounds__(256) void composite_kernel(
    const float4* __restrict__ s0, const float4* __restrict__ s1,
    const float4* __restrict__ sbb, const float* __restrict__ sa,
    const int* __restrict__ Wp, const int* __restrict__ Hp,
    float4* __restrict__ part, int n, int npix) {
    __shared__ float bx0[CH], bx1[CH], by0[CH], by1[CH];
    __shared__ float4 l0[CH], l1[CH];
    __shared__ float  la[CH];

    int tid = threadIdx.x;
    int lane = tid & 63;
    int wv = tid >> 6;
    int W = *Wp, H = *Hp;
    int qpx = (W + 7) >> 3;
    int quads = qpx * ((H + 7) >> 3);

    int seg = blockIdx.y;
    int seglen = (n + NSEG - 1) / NSEG;
    int gbeg = seg * seglen;
    int gend = min(n, gbeg + seglen);
    int m = gend - gbeg;                    // may be <= CH
    int mpad = (m + 63) & ~63;

    // stage segment into LDS (SoA bbox to keep lane reads stride-4B)
    for (int t = tid; t < mpad; t += 256) {
        if (t < m) {
            float4 bbx = sbb[gbeg + t];
            bx0[t] = bbx.x; bx1[t] = bbx.y; by0[t] = bbx.z; by1[t] = bbx.w;
            l0[t] = s0[gbeg + t];
            l1[t] = s1[gbeg + t];
            la[t] = sa[gbeg + t];
        } else {
            bx0[t] = 3.0e38f; bx1[t] = -3.0e38f; by0[t] = 3.0e38f; by1[t] = -3.0e38f;
        }
    }
    __syncthreads();

    int quad = blockIdx.x * 4 + wv;
    if (quad >= quads) return;              // wave-uniform; no barriers below
    int qx = quad % qpx, qy = quad / qpx;
    int col = qx * 8 + (lane & 7);
    int row = qy * 8 + (lane >> 3);
    float cxofx = (W * 0.5f) / FXc, cyofy = (H * 0.5f) / FYc;
    float px = ((float)col + 0.5f) / FXc - cxofx;
    float py = ((float)row + 0.5f) / FYc - cyofy;
    float wx0 = ((float)(qx*8)   + 0.5f) / FXc - cxofx;
    float wx1 = ((float)(qx*8+7) + 0.5f) / FXc - cxofx;
    float wy0 = ((float)(qy*8)   + 0.5f) / FYc - cyofy;
    float wy1 = ((float)(qy*8+7) + 0.5f) / FYc - cyofy;

    float T = 1.0f, r = 0.0f, g = 0.0f, b = 0.0f;
    int nit = mpad >> 6;
    for (int it = 0; it < nit; ++it) {
        int j = (it << 6) + lane;
        bool hit = !(bx1[j] < wx0 || bx0[j] > wx1 || by1[j] < wy0 || by0[j] > wy1);
        unsigned long long msk = __ballot(hit);
        int base = it << 6;
        while (msk) {                       // ascending j = front-to-back
            int t = __builtin_ctzll(msk);
            msk &= msk - 1;
            int jj = base + t;
            float4 a0 = l0[jj];             // LDS broadcast
            float4 a1 = l1[jj];
            float  al = la[jj];
            float dx = px - a0.x;
            float dy = py - a0.y;
            float pw = dx * (a0.z * dx + a0.w * dy) + a1.x * dy * dy;
            float w  = al * __expf(pw);
            w = fminf(w, 0.999f);
            w = (w > THRESHc) ? w : 0.0f;
            float wT = w * T;
            r = fmaf(wT, a1.y, r);
            g = fmaf(wT, a1.z, g);
            b = fmaf(wT, a1.w, b);
            T = T - wT;
        }
    }
    if (col < W && row < H) {
        int p = row * W + col;
        part[(size_t)seg * npix + p] = make_float4(r, g, b, T);
    }
}

// ---- combine segment partials front-to-back --------------------------------
__global__ __launch_bounds__(256) void combine_kernel(
    const float4* __restrict__ part, float* __restrict__ out, int npix) {
    int p = blockIdx.x * 256 + threadIdx.x;
    if (p >= npix) return;
    float T = 1.0f, r = 0.0f, g = 0.0f, b = 0.0f;
#pragma unroll
    for (int s = 0; s < NSEG; ++s) {
        float4 v = part[(size_t)s * npix + p];
        r = fmaf(T, v.x, r);
        g = fmaf(T, v.y, g);
        b = fmaf(T, v.z, b);
        T *= v.w;
    }
    out[3*p+0] = r;
    out[3*p+1] = g;
    out[3*p+2] = b;
}

extern "C" void kernel_launch(void* const* d_in, const int* in_sizes, int n_in,
                              void* d_out, int out_size, void* d_ws, size_t ws_size,
                              hipStream_t stream) {
    const float* mean  = (const float*)d_in[0];
    const float* qvec  = (const float*)d_in[1];
    const float* svec  = (const float*)d_in[2];
    const float* color = (const float*)d_in[3];
    const float* alpha = (const float*)d_in[4];
    const float* c2w   = (const float*)d_in[5];
    const int*   Hp    = (const int*)d_in[6];
    const int*   Wp    = (const int*)d_in[7];
    float* out = (float*)d_out;

    int n = in_sizes[0] / 3;
    int npix = out_size / 3;

    char* ws = (char*)d_ws;
    float4* s0  = (float4*)ws; ws += (size_t)n * sizeof(float4);
    float4* s1  = (float4*)ws; ws += (size_t)n * sizeof(float4);
    float4* sbb = (float4*)ws; ws += (size_t)n * sizeof(float4);
    float4* part = (float4*)ws; ws += (size_t)npix * NSEG * sizeof(float4);
    float*  sa  = (float*)ws;  ws += (size_t)n * sizeof(float);

    int nblocks = (n + 3) / 4;
    prep_kernel<<<nblocks, 256, 0, stream>>>(mean, qvec, svec, color, alpha, c2w,
                                             s0, s1, sbb, sa, n);

    int Wh = 128;                           // problem constant; device reads W,H
    int Hh = npix / Wh;
    int quads = ((Wh + 7) / 8) * ((Hh + 7) / 8);
    dim3 grid((quads + 3) / 4, NSEG);
    composite_kernel<<<grid, 256, 0, stream>>>(s0, s1, sbb, sa, Wp, Hp, part, n, npix);

    combine_kernel<<<(npix + 255) / 256, 256, 0, stream>>>(part, out, npix);
}

// Round 7
// 18.451 us; speedup vs baseline: 5.0799x; 1.0365x over previous
//
#include <hip/hip_runtime.h>

#define FXc 160.0f
#define FYc 160.0f
#define THRESHc 0.001f
#define EPSc 1e-6f
#define SORT_CAP 2048
#define NSEG 16

// ---- fused preprocess + wave-parallel rank + scatter (unchanged from R5) ----
__global__ __launch_bounds__(256) void prep_kernel(
    const float* __restrict__ mean, const float* __restrict__ qvec,
    const float* __restrict__ svec, const float* __restrict__ color,
    const float* __restrict__ alpha, const float* __restrict__ c2w,
    float4* __restrict__ s0, float4* __restrict__ s1,
    float4* __restrict__ sbb, float* __restrict__ sa, int n) {
    __shared__ float dep[SORT_CAP];
    int tid = threadIdx.x;
    int lane = tid & 63;
    int wv = tid >> 6;
    int i = blockIdx.x * 4 + wv;

    float tx = c2w[3], ty = c2w[7], tz = c2w[11];
    float W00 = c2w[0], W01 = c2w[4], W02 = c2w[8];
    float W10 = c2w[1], W11 = c2w[5], W12 = c2w[9];
    float W20 = c2w[2], W21 = c2w[6], W22 = c2w[10];

    int ncap = (n + 63) & ~63;
    for (int k = tid; k < ncap; k += 256) {
        float d = 3.0e38f;
        if (k < n) {
            float mx = mean[3*k+0] - tx, my = mean[3*k+1] - ty, mz = mean[3*k+2] - tz;
            d = W20*mx + W21*my + W22*mz;
        }
        dep[k] = d;
    }
    __syncthreads();
    if (i >= n) return;

    float di = dep[i];
    int nit = ncap >> 6;
    int rank = 0;
    for (int it = 0; it < nit; ++it) {
        int j = (it << 6) + lane;
        float dj = dep[j];
        bool c = (dj < di) || (dj == di && j < i);
        rank += (int)__popcll(__ballot(c));
    }

    float mx = mean[3*i+0] - tx, my = mean[3*i+1] - ty, mz = mean[3*i+2] - tz;
    float pmx = W00*mx + W01*my + W02*mz;
    float pmy = W10*mx + W11*my + W12*mz;
    float pmz = W20*mx + W21*my + W22*mz;

    float qw = qvec[4*i+0], qx = qvec[4*i+1], qy = qvec[4*i+2], qz = qvec[4*i+3];
    float qinv = rsqrtf(qw*qw + qx*qx + qy*qy + qz*qz);
    qw *= qinv; qx *= qinv; qy *= qinv; qz *= qinv;
    float R00 = 1.0f - 2.0f*(qy*qy + qz*qz), R01 = 2.0f*(qx*qy - qw*qz), R02 = 2.0f*(qx*qz + qw*qy);
    float R10 = 2.0f*(qx*qy + qw*qz), R11 = 1.0f - 2.0f*(qx*qx + qz*qz), R12 = 2.0f*(qy*qz - qw*qx);
    float R20 = 2.0f*(qx*qz - qw*qy), R21 = 2.0f*(qy*qz + qw*qx), R22 = 1.0f - 2.0f*(qx*qx + qy*qy);
    float sx = svec[3*i+0], sy = svec[3*i+1], sz = svec[3*i+2];
    float M00 = R00*sx, M01 = R01*sy, M02 = R02*sz;
    float M10 = R10*sx, M11 = R11*sy, M12 = R12*sz;
    float M20 = R20*sx, M21 = R21*sy, M22 = R22*sz;

    float iz = 1.0f / pmz, iz2 = iz*iz;
    float axx = pmx*iz2, ayy = pmy*iz2;
    float A0 = iz*W00 - axx*W20, A1 = iz*W01 - axx*W21, A2 = iz*W02 - axx*W22;
    float B0 = iz*W10 - ayy*W20, B1 = iz*W11 - ayy*W21, B2 = iz*W12 - ayy*W22;
    float V00 = A0*M00 + A1*M10 + A2*M20;
    float V01 = A0*M01 + A1*M11 + A2*M21;
    float V02 = A0*M02 + A1*M12 + A2*M22;
    float V10 = B0*M00 + B1*M10 + B2*M20;
    float V11 = B0*M01 + B1*M11 + B2*M21;
    float V12 = B0*M02 + B1*M12 + B2*M22;
    float a  = V00*V00 + V01*V01 + V02*V02 + EPSc;
    float bb = V00*V10 + V01*V11 + V02*V12;
    float dd = V10*V10 + V11*V11 + V12*V12 + EPSc;
    float det  = a*dd - bb*bb;
    float idet = 1.0f / det;
    float h00 = -0.5f * dd * idet;
    float h01 =  bb * idet;
    float h11 = -0.5f * a  * idet;

    float al = alpha[i];
    float m2x = pmx*iz, m2y = pmy*iz;
    float x0, x1, y0, y1;
    if (al > THRESHc) {
        float c = logf(al / THRESHc);
        float ex = sqrtf(2.0f*c*a)  * 1.0009f + 1e-6f;
        float ey = sqrtf(2.0f*c*dd) * 1.0009f + 1e-6f;
        x0 = m2x - ex; x1 = m2x + ex;
        y0 = m2y - ey; y1 = m2y + ey;
    } else {
        x0 = 3.0e38f; x1 = -3.0e38f; y0 = 3.0e38f; y1 = -3.0e38f;
    }

    if (lane == 0) {
        s0[rank]  = make_float4(m2x, m2y, h00, h01);
        s1[rank]  = make_float4(h11, color[3*i+0], color[3*i+1], color[3*i+2]);
        sbb[rank] = make_float4(x0, x1, y0, y1);
        sa[rank]  = al;
    }
}

// ---- render: block = one 8x8 quad; 16 waves = 16 depth segments; in-block
//      combine via LDS. No part buffer, no third kernel. ----------------------
__global__ __launch_bounds__(1024) void render_kernel(
    const float4* __restrict__ s0, const float4* __restrict__ s1,
    const float4* __restrict__ sbb, const float* __restrict__ sa,
    const int* __restrict__ Wp, const int* __restrict__ Hp,
    float* __restrict__ out, int n) {
    __shared__ float4 partial[NSEG][64];
    int tid = threadIdx.x;
    int lane = tid & 63;
    int w = tid >> 6;                        // wave index = depth segment
    int W = *Wp, H = *Hp;
    int qpx = (W + 7) >> 3;
    int q = blockIdx.x;
    int qx = q % qpx, qy = q / qpx;
    int col = qx * 8 + (lane & 7);
    int row = qy * 8 + (lane >> 3);
    float cxofx = (W * 0.5f) / FXc, cyofy = (H * 0.5f) / FYc;
    float px = ((float)col + 0.5f) / FXc - cxofx;
    float py = ((float)row + 0.5f) / FYc - cyofy;
    // wave-uniform quadrant pixel-center bounds (same for all 16 waves)
    float wx0 = ((float)(qx*8)   + 0.5f) / FXc - cxofx;
    float wx1 = ((float)(qx*8+7) + 0.5f) / FXc - cxofx;
    float wy0 = ((float)(qy*8)   + 0.5f) / FYc - cyofy;
    float wy1 = ((float)(qy*8+7) + 0.5f) / FYc - cyofy;

    int seglen = (n + NSEG - 1) / NSEG;
    int gbeg = w * seglen;
    int gend = min(n, gbeg + seglen);

    float T = 1.0f, r = 0.0f, g = 0.0f, b = 0.0f;
    for (int base = gbeg; base < gend; base += 64) {
        int j = base + lane;
        bool hit = false;
        if (j < gend) {
            float4 bbx = sbb[j];             // coalesced, L2-hot
            hit = !(bbx.y < wx0 || bbx.x > wx1 || bbx.w < wy0 || bbx.z > wy1);
        }
        unsigned long long msk = __ballot(hit);
        while (msk) {                        // ascending j = front-to-back
            int t = __builtin_ctzll(msk);
            msk &= msk - 1;
            int jj = base + t;
            float4 a0 = s0[jj];              // uniform-address L2 broadcast
            float4 a1 = s1[jj];
            float  al = sa[jj];
            float dx = px - a0.x;
            float dy = py - a0.y;
            float pw = dx * (a0.z * dx + a0.w * dy) + a1.x * dy * dy;
            float ww = al * __expf(pw);
            ww = fminf(ww, 0.999f);
            ww = (ww > THRESHc) ? ww : 0.0f;
            float wT = ww * T;
            r = fmaf(wT, a1.y, r);
            g = fmaf(wT, a1.z, g);
            b = fmaf(wT, a1.w, b);
            T = T - wT;
        }
    }
    partial[w][lane] = make_float4(r, g, b, T);
    __syncthreads();

    if (tid < 64) {                          // wave 0 folds segments in depth order
        float Tf = 1.0f, rf = 0.0f, gf = 0.0f, bf = 0.0f;
#pragma unroll
        for (int s = 0; s < NSEG; ++s) {
            float4 v = partial[s][tid];
            rf = fmaf(Tf, v.x, rf);
            gf = fmaf(Tf, v.y, gf);
            bf = fmaf(Tf, v.z, bf);
            Tf *= v.w;
        }
        if (col < W && row < H) {
            int p = row * W + col;
            out[3*p+0] = rf;
            out[3*p+1] = gf;
            out[3*p+2] = bf;
        }
    }
}

extern "C" void kernel_launch(void* const* d_in, const int* in_sizes, int n_in,
                              void* d_out, int out_size, void* d_ws, size_t ws_size,
                              hipStream_t stream) {
    const float* mean  = (const float*)d_in[0];
    const float* qvec  = (const float*)d_in[1];
    const float* svec  = (const float*)d_in[2];
    const float* color = (const float*)d_in[3];
    const float* alpha = (const float*)d_in[4];
    const float* c2w   = (const float*)d_in[5];
    const int*   Hp    = (const int*)d_in[6];
    const int*   Wp    = (const int*)d_in[7];
    float* out = (float*)d_out;

    int n = in_sizes[0] / 3;
    int npix = out_size / 3;

    char* ws = (char*)d_ws;
    float4* s0  = (float4*)ws; ws += (size_t)n * sizeof(float4);
    float4* s1  = (float4*)ws; ws += (size_t)n * sizeof(float4);
    float4* sbb = (float4*)ws; ws += (size_t)n * sizeof(float4);
    float*  sa  = (float*)ws;  ws += (size_t)n * sizeof(float);

    int nblocks = (n + 3) / 4;
    prep_kernel<<<nblocks, 256, 0, stream>>>(mean, qvec, svec, color, alpha, c2w,
                                             s0, s1, sbb, sa, n);

    int Wh = 128;                            // problem constant; device reads W,H
    int Hh = npix / Wh;
    int quads = ((Wh + 7) / 8) * ((Hh + 7) / 8);
    render_kernel<<<quads, 1024, 0, stream>>>(s0, s1, sbb, sa, Wp, Hp, out, n);
}